// Round 3
// baseline (257.415 us; speedup 1.0000x reference)
//
#include <hip/hip_runtime.h>
#include <hip/hip_bf16.h>

#define BB 32
#define SS 64
#define DD 256
#define HH 8
#define HDIM 32
#define NSS 65
#define LN_EPS 1e-5f

// ---------------- ws layout (float offsets) ----------------
#define OFF_DESC   0u            // B*S*D   = 524288
#define OFF_U      524288u       // 524288  (be1 + bg-path folded in)
#define OFF_V      1048576u      // 524288  (bg-path folded in)
#define OFF_VBUF   1572864u      // B*NS*D  = 532480
#define OFF_NA     2105344u      // B*NS*NS = 135200
#define OFF_PK     2240544u      // 4096   (256 x 16: lng,lnb,Mf[0..7],pad)
#define OFF_CUT    2244640u      // 65536  (We1a@Wg)^T
#define OFF_CVT    2310176u      // 65536  (We1b@Wg)^T
#define OFF_BU     2375712u      // 256
#define OFF_BV     2375968u      // 256
#define OFF_SQ     2376224u      // 16640
#define OFF_SK     2392864u      // 16640
#define OFF_CTX    2409504u      // 532480
#define OFF_WGT    2941984u      // 65536
#define OFF_WE1AT  3007520u      // 65536
#define OFF_WE1BT  3073056u      // 65536
#define OFF_WVT    3138592u      // 65536
#define OFF_WOT    3204128u      // 65536
#define OFF_WQF    3269664u      // 2048
#define OFF_WKF    3271712u      // 2048
#define OFF_CVEC   3273760u      // 32
#define OFF_RND    3273792u      // 2048
#define OFF_RNV    3275840u      // 2048
// total 3277888 floats = 13.1 MB

// out[r0+r][o] = bias[o] + sum_k in[r0+r][k] * WT[k][o], 16 rows, 256 threads(o)
__device__ __forceinline__ void gemm16_body(const float* __restrict__ in,
                                            const float* __restrict__ WT,
                                            const float* __restrict__ bias,
                                            float* __restrict__ out,
                                            int r0, int addBias, float* vals) {
    int o = threadIdx.x;
    const float* __restrict__ x = in + (size_t)r0 * DD;   // uniform -> s_load
    float acc[16];
    #pragma unroll
    for (int r = 0; r < 16; ++r) acc[r] = 0.f;
    #pragma unroll 4
    for (int k = 0; k < DD; ++k) {
        float w = WT[(size_t)k * DD + o];
        #pragma unroll
        for (int r = 0; r < 16; ++r)
            acc[r] = fmaf(x[r * DD + k], w, acc[r]);
    }
    float bb = addBias ? bias[o] : 0.f;
    #pragma unroll
    for (int r = 0; r < 16; ++r) {
        float v = acc[r] + bb;
        out[(size_t)(r0 + r) * DD + o] = v;
        vals[r] = v;
    }
}

// ---- prep_a: 5 transposes + attn folds + PK + bias folds (91 blocks) ----
__global__ __launch_bounds__(256) void prep_a(
    const float* __restrict__ Wg, const float* __restrict__ We1,
    const float* __restrict__ Wv, const float* __restrict__ Wo,
    const float* __restrict__ Wq, const float* __restrict__ bq,
    const float* __restrict__ Wk, const float* __restrict__ bk,
    const float* __restrict__ We2, const float* __restrict__ be2,
    const float* __restrict__ Wa, const float* __restrict__ lng,
    const float* __restrict__ lnb, const float* __restrict__ bg,
    const float* __restrict__ be1,
    float* __restrict__ WgT, float* __restrict__ We1aT, float* __restrict__ We1bT,
    float* __restrict__ WvT, float* __restrict__ WoT,
    float* __restrict__ wqf, float* __restrict__ wkf,
    float* __restrict__ PK, float* __restrict__ cvec,
    float* __restrict__ bu, float* __restrict__ bv) {
    __shared__ float t[64][65];
    int blk = blockIdx.x;
    if (blk < 80) {
        int which = blk >> 4, t16 = blk & 15;
        const float* src; float* dst; int ld, c0;
        if (which == 0)      { src = Wg;  dst = WgT;   ld = 256; c0 = 0; }
        else if (which == 1) { src = We1; dst = We1aT; ld = 512; c0 = 0; }
        else if (which == 2) { src = We1; dst = We1bT; ld = 512; c0 = 256; }
        else if (which == 3) { src = Wv;  dst = WvT;   ld = 256; c0 = 0; }
        else                 { src = Wo;  dst = WoT;   ld = 256; c0 = 0; }
        int to = t16 & 3, tk = t16 >> 2;
        int tx = threadIdx.x & 63, ty = threadIdx.x >> 6;
        #pragma unroll
        for (int r = ty; r < 64; r += 4)
            t[r][tx] = src[(size_t)(to * 64 + r) * ld + c0 + tk * 64 + tx];
        __syncthreads();
        #pragma unroll
        for (int r = ty; r < 64; r += 4)
            dst[(size_t)(tk * 64 + r) * DD + to * 64 + tx] = t[tx][r];
    } else if (blk < 88) {
        int h = blk - 80, in = threadIdx.x;
        float aq = 0.f, ak = 0.f, ae = 0.f;
        #pragma unroll
        for (int d = 0; d < HDIM; ++d) {
            aq = fmaf(Wq[(h * HDIM + d) * DD + in], Wa[d], aq);
            ak = fmaf(Wk[(h * HDIM + d) * DD + in], Wa[HDIM + d], ak);
            ae = fmaf(We2[(h * HDIM + d) * DD + in], Wa[2 * HDIM + d], ae);
        }
        wqf[h * DD + in] = aq;
        wkf[h * DD + in] = ak;
        PK[in * 16 + 2 + h] = ae;
        if (in == 0) {
            float cq = 0.f, ck = 0.f, ce = 0.f;
            for (int d = 0; d < HDIM; ++d) {
                cq = fmaf(bq[h * HDIM + d], Wa[d], cq);
                ck = fmaf(bk[h * HDIM + d], Wa[HDIM + d], ck);
                ce = fmaf(be2[h * HDIM + d], Wa[2 * HDIM + d], ce);
            }
            cvec[h] = cq; cvec[8 + h] = ck; cvec[16 + h] = ce;
        }
    } else if (blk == 88) {
        int d = threadIdx.x;
        PK[d * 16 + 0] = lng[d];
        PK[d * 16 + 1] = lnb[d];
        #pragma unroll
        for (int c = 10; c < 16; ++c) PK[d * 16 + c] = 0.f;
    } else if (blk == 89) {
        int o = threadIdx.x;
        float a = be1[o];
        for (int m = 0; m < DD; ++m) a = fmaf(We1[(size_t)o * 512 + m], bg[m], a);
        bu[o] = a;
    } else {
        int o = threadIdx.x;
        float a = 0.f;
        for (int m = 0; m < DD; ++m) a = fmaf(We1[(size_t)o * 512 + 256 + m], bg[m], a);
        bv[o] = a;
    }
}

// ---- prep_b: CuT = WgT @ We1aT, CvT = WgT @ We1bT (32 blocks) ----
__global__ __launch_bounds__(256) void prep_b(
    const float* __restrict__ WgT, const float* __restrict__ We1aT,
    const float* __restrict__ We1bT, float* __restrict__ CuT,
    float* __restrict__ CvT) {
    float vals[16];
    int blk = blockIdx.x;
    if (blk < 16) gemm16_body(WgT, We1aT, nullptr, CuT, blk * 16, 0, vals);
    else          gemm16_body(WgT, We1bT, nullptr, CvT, (blk - 16) * 16, 0, vals);
}

// ---- proj: desc(+rnd), U, V, vbuf, sqsk, rnv — all from raw inputs (772 blocks) ----
__global__ __launch_bounds__(256) void proj_kernel(
    const float* __restrict__ X, const float* __restrict__ nve,
    const float* __restrict__ WgT, const float* __restrict__ CuT,
    const float* __restrict__ CvT, const float* __restrict__ WvT,
    const float* __restrict__ bg, const float* __restrict__ bu,
    const float* __restrict__ bv, const float* __restrict__ bwv,
    const float* __restrict__ wqf, const float* __restrict__ wkf,
    const float* __restrict__ cvec,
    float* __restrict__ desc, float* __restrict__ U, float* __restrict__ V,
    float* __restrict__ vbuf, float* __restrict__ sq, float* __restrict__ sk,
    float* __restrict__ rnd, float* __restrict__ rnv) {
    __shared__ float red[4][16];
    float vals[16];
    int blk = blockIdx.x;
    if (blk < 128) {
        gemm16_body(X, WgT, bg, desc, blk * 16, 1, vals);
        int w = threadIdx.x >> 6, lane = threadIdx.x & 63;
        #pragma unroll
        for (int r = 0; r < 16; ++r) {
            float s2 = vals[r] * vals[r];
            #pragma unroll
            for (int off = 32; off; off >>= 1) s2 += __shfl_xor(s2, off);
            if (lane == 0) red[w][r] = s2;
        }
        __syncthreads();
        if (threadIdx.x < 16) {
            float s = red[0][threadIdx.x] + red[1][threadIdx.x] +
                      red[2][threadIdx.x] + red[3][threadIdx.x];
            rnd[blk * 16 + threadIdx.x] = 1.f / sqrtf(s);
        }
    } else if (blk < 256) {
        gemm16_body(X, CuT, bu, U, (blk - 128) * 16, 1, vals);
    } else if (blk < 384) {
        gemm16_body(X, CvT, bv, V, (blk - 256) * 16, 1, vals);
    } else if (blk < 514) {
        gemm16_body(nve, WvT, bwv, vbuf, (blk - 384) * 16, 1, vals);
    } else if (blk < 644) {
        int r0 = (blk - 514) * 16;
        int lr = threadIdx.x >> 4, tq = threadIdx.x & 15;
        int g = r0 + lr, b = g / NSS, ii = g % NSS;
        const float* __restrict__ x = nve + (size_t)g * DD;
        const float* __restrict__ wv = ((tq < 8) ? wqf : wkf) + (tq & 7) * DD;
        float acc = 0.f;
        #pragma unroll 8
        for (int k = 0; k < DD; ++k) acc = fmaf(x[k], wv[k], acc);
        int h = tq & 7;
        if (tq < 8) sq[(size_t)(b * HH + h) * NSS + ii] = acc + cvec[h];
        else        sk[(size_t)(b * HH + h) * NSS + ii] = acc + cvec[8 + h];
    } else {
        int r0 = (blk - 644) * 16;
        int lr = threadIdx.x >> 4, tq = threadIdx.x & 15;
        int g = r0 + lr, b = g >> 6, s = g & 63;
        const float* __restrict__ x = nve + (size_t)(b * NSS + 1 + s) * DD;
        float ssum = 0.f;
        for (int k = tq; k < DD; k += 16) ssum = fmaf(x[k], x[k], ssum);
        ssum += __shfl_xor(ssum, 1);
        ssum += __shfl_xor(ssum, 2);
        ssum += __shfl_xor(ssum, 4);
        ssum += __shfl_xor(ssum, 8);
        if (tq == 0) rnv[g] = 1.f / sqrtf(ssum);
    }
}

// ---- adjacency: direct-load grams, wave per i, 4 i per block (512 blocks) ----
__global__ __launch_bounds__(256) void adj_kernel(
    const float* __restrict__ desc, const float* __restrict__ nve,
    const float* __restrict__ rnd, const float* __restrict__ rnv,
    const float* __restrict__ tb, float* __restrict__ na) {
    int b = blockIdx.x >> 4;
    int w = threadIdx.x >> 6, lane = threadIdx.x & 63;
    int i = __builtin_amdgcn_readfirstlane(((blockIdx.x & 15) << 2) + w);
    const float4* __restrict__ drow = (const float4*)(desc + (size_t)(b * SS + i) * DD);
    const float4* __restrict__ dcol = (const float4*)(desc + (size_t)(b * SS + lane) * DD);
    float dot = 0.f;
    #pragma unroll 8
    for (int f = 0; f < 64; ++f) {
        float4 u = drow[f], v = dcol[f];
        dot = fmaf(u.x, v.x, dot); dot = fmaf(u.y, v.y, dot);
        dot = fmaf(u.z, v.z, dot); dot = fmaf(u.w, v.w, dot);
    }
    float gsim = dot * rnd[b * SS + i] * rnd[b * SS + lane];
    bool flag = (gsim + tb[0] > 0.f) && (i != lane);
    const float4* __restrict__ vrow = (const float4*)(nve + (size_t)(b * NSS + 1 + i) * DD);
    const float4* __restrict__ vcol = (const float4*)(nve + (size_t)(b * NSS + 1 + lane) * DD);
    float dv = 0.f;
    #pragma unroll 8
    for (int f = 0; f < 64; ++f) {
        float4 u = vrow[f], v = vcol[f];
        dv = fmaf(u.x, v.x, dv); dv = fmaf(u.y, v.y, dv);
        dv = fmaf(u.z, v.z, dv); dv = fmaf(u.w, v.w, dv);
    }
    float ssim = dv * rnv[b * SS + i] * rnv[b * SS + lane];
    float P = flag ? ssim : 0.f;
    float m = P;
    #pragma unroll
    for (int off = 32; off; off >>= 1) m = fmaxf(m, __shfl_xor(m, off));
    float e = __expf(P - m);
    float s = e;
    #pragma unroll
    for (int off = 32; off; off >>= 1) s += __shfl_xor(s, off);
    na[(size_t)(b * NSS + i + 1) * NSS + lane + 1] = e / s;
    if (lane == 0) na[(size_t)(b * NSS + i + 1) * NSS] = 0.f;
    if (i == 0) {
        na[(size_t)b * NSS * NSS + lane + 1] = 1.f;
        if (lane == 0) na[(size_t)b * NSS * NSS] = 0.f;
    }
}

// ---- se+attn fused: block = 2 i-rows x 2 d-halves (+ border tile), lane = j ----
__global__ __launch_bounds__(256) void se_attn_kernel(
    const float* __restrict__ U, const float* __restrict__ V,
    const float* __restrict__ PK, const float* __restrict__ cvec,
    const float* __restrict__ na, const float* __restrict__ sq,
    const float* __restrict__ sk, const float* __restrict__ ba,
    const float* __restrict__ vbuf, float* __restrict__ aw,
    float* __restrict__ ctx) {
    __shared__ float2 stat[4][64];
    __shared__ float sep[4][64][HH];
    int blk = blockIdx.x;
    int b = blk / 33, itile = blk % 33;
    int w = threadIdx.x >> 6, lane = threadIdx.x & 63;
    int z = w >> 1, dh = w & 1;
    bool border = (itile == 32);
    int i = border ? 0 : (itile * 2 + z + 1);
    int i_f = __builtin_amdgcn_readfirstlane(i);
    int d0 = dh * 128;
    const float4* __restrict__ vptr = (const float4*)(V + (size_t)(b * SS + lane) * DD + d0);
    const float4* __restrict__ uptr;
    if (border) {
        uptr = (const float4*)(U + (size_t)(b * SS + lane) * DD + d0);
    } else {
        int iu = __builtin_amdgcn_readfirstlane(b * SS + itile * 2 + z);
        uptr = (const float4*)(U + (size_t)iu * DD + d0);
    }
    // pass 1: partial LN stats over this wave's 128 d's (per-lane, no shuffles)
    float ss = 0.f, s2 = 0.f;
    #pragma unroll 8
    for (int f = 0; f < 32; ++f) {
        float4 u = uptr[f], v = vptr[f];
        float t0 = u.x + v.x, t1 = u.y + v.y, t2 = u.z + v.z, t3 = u.w + v.w;
        ss += (t0 + t1) + (t2 + t3);
        s2 = fmaf(t0, t0, s2); s2 = fmaf(t1, t1, s2);
        s2 = fmaf(t2, t2, s2); s2 = fmaf(t3, t3, s2);
    }
    stat[w][lane] = make_float2(ss, s2);
    __syncthreads();
    float2 sA = stat[z * 2][lane], sB = stat[z * 2 + 1][lane];
    float mu = (sA.x + sB.x) * (1.f / DD);
    float var = fmaf(-mu, mu, (sA.y + sB.y) * (1.f / DD));
    float rstd = rsqrtf(var + LN_EPS);
    // pass 2: partial head-dots over this wave's 128 d's
    float part[HH];
    #pragma unroll
    for (int h = 0; h < HH; ++h) part[h] = 0.f;
    #pragma unroll 4
    for (int f = 0; f < 32; ++f) {
        float4 u = uptr[f], v = vptr[f];
        float t[4] = {u.x + v.x, u.y + v.y, u.z + v.z, u.w + v.w};
        const float* __restrict__ pk = PK + (size_t)(d0 + 4 * f) * 16;
        #pragma unroll
        for (int c = 0; c < 4; ++c) {
            const float* p = pk + c * 16;
            float xn = fmaf((t[c] - mu) * rstd, p[0], p[1]);
            float r = fmaxf(xn, 0.f);
            #pragma unroll
            for (int h = 0; h < HH; ++h)
                part[h] = fmaf(r, p[2 + h], part[h]);
        }
    }
    #pragma unroll
    for (int h = 0; h < HH; ++h) sep[w][lane][h] = part[h];
    __syncthreads();
    // attn: wave handles row i(z), heads [dh*4, dh*4+4)
    float nav = na[(size_t)(b * NSS + i_f) * NSS + lane + 1];
    float bav = ba[0];
    #pragma unroll
    for (int hh = 0; hh < 4; ++hh) {
        int h = dh * 4 + hh;
        float sev = sep[z * 2][lane][h] + sep[z * 2 + 1][lane][h];
        float se_val = nav * (sev + cvec[16 + h]);
        float score = sq[(size_t)(b * HH + h) * NSS + i_f] +
                      sk[(size_t)(b * HH + h) * NSS + 1 + lane] + se_val + bav;
        float m = score;
        #pragma unroll
        for (int off = 32; off; off >>= 1) m = fmaxf(m, __shfl_xor(m, off));
        float e = __expf(score - m);
        float tot = e;
        #pragma unroll
        for (int off = 32; off; off >>= 1) tot += __shfl_xor(tot, off);
        float aval = e / tot;
        float* awrow = aw + ((size_t)(b * HH + h) * NSS + i_f) * NSS;
        awrow[1 + lane] = aval;
        if (lane == 0) awrow[0] = 0.f;
        // ctx[i, h*32+d] = sum_j aval(j) * vbuf[b, 1+j, h*32+d]
        int d = lane & 31, joff = lane >> 5;
        float acc = 0.f;
        #pragma unroll 8
        for (int j2 = 0; j2 < 32; ++j2) {
            int jj = (j2 << 1) | joff;
            float a_j = __shfl(aval, jj);
            acc = fmaf(a_j, vbuf[(size_t)(b * NSS + 1 + jj) * DD + h * HDIM + d], acc);
        }
        acc += __shfl_xor(acc, 32);
        if (lane < 32) ctx[(size_t)(b * NSS + i_f) * DD + h * HDIM + d] = acc;
    }
}

// ---- out = ctx @ WoT + bo (130 blocks) ----
__global__ __launch_bounds__(256) void outgemm_kernel(
    const float* __restrict__ ctx, const float* __restrict__ WoT,
    const float* __restrict__ bo, float* __restrict__ out) {
    float vals[16];
    gemm16_body(ctx, WoT, bo, out, blockIdx.x * 16, 1, vals);
}

extern "C" void kernel_launch(void* const* d_in, const int* in_sizes, int n_in,
                              void* d_out, int out_size, void* d_ws, size_t ws_size,
                              hipStream_t stream) {
    const float* desc_emb = (const float*)d_in[0];
    const float* nve      = (const float*)d_in[1];
    const float* Wg  = (const float*)d_in[2];
    const float* bg  = (const float*)d_in[3];
    const float* Wq  = (const float*)d_in[4];
    const float* bq  = (const float*)d_in[5];
    const float* Wk  = (const float*)d_in[6];
    const float* bk  = (const float*)d_in[7];
    const float* Wv  = (const float*)d_in[8];
    const float* bv_in = (const float*)d_in[9];
    const float* We1 = (const float*)d_in[10];
    const float* be1 = (const float*)d_in[11];
    const float* lng = (const float*)d_in[12];
    const float* lnb = (const float*)d_in[13];
    const float* We2 = (const float*)d_in[14];
    const float* be2 = (const float*)d_in[15];
    const float* Wa  = (const float*)d_in[16];
    const float* ba  = (const float*)d_in[17];
    const float* Wo  = (const float*)d_in[18];
    const float* bo  = (const float*)d_in[19];
    const float* tb  = (const float*)d_in[20];

    float* ws   = (float*)d_ws;
    float* desc = ws + OFF_DESC;
    float* U    = ws + OFF_U;
    float* V    = ws + OFF_V;
    float* vbuf = ws + OFF_VBUF;
    float* na   = ws + OFF_NA;
    float* PK   = ws + OFF_PK;
    float* CuT  = ws + OFF_CUT;
    float* CvT  = ws + OFF_CVT;
    float* bu   = ws + OFF_BU;
    float* bv   = ws + OFF_BV;
    float* sq   = ws + OFF_SQ;
    float* sk   = ws + OFF_SK;
    float* ctx  = ws + OFF_CTX;
    float* WgT   = ws + OFF_WGT;
    float* We1aT = ws + OFF_WE1AT;
    float* We1bT = ws + OFF_WE1BT;
    float* WvT   = ws + OFF_WVT;
    float* WoT   = ws + OFF_WOT;
    float* wqf  = ws + OFF_WQF;
    float* wkf  = ws + OFF_WKF;
    float* cvec = ws + OFF_CVEC;
    float* rnd  = ws + OFF_RND;
    float* rnv  = ws + OFF_RNV;

    float* out = (float*)d_out;                  // [B][NS][D]
    float* aw  = out + (size_t)BB * NSS * DD;    // [B][H][NS][NS]

    prep_a<<<91, 256, 0, stream>>>(Wg, We1, Wv, Wo, Wq, bq, Wk, bk, We2, be2,
                                   Wa, lng, lnb, bg, be1,
                                   WgT, We1aT, We1bT, WvT, WoT,
                                   wqf, wkf, PK, cvec, bu, bv);
    prep_b<<<32, 256, 0, stream>>>(WgT, We1aT, We1bT, CuT, CvT);
    proj_kernel<<<772, 256, 0, stream>>>(desc_emb, nve, WgT, CuT, CvT, WvT,
                                         bg, bu, bv, bv_in, wqf, wkf, cvec,
                                         desc, U, V, vbuf, sq, sk, rnd, rnv);
    adj_kernel<<<512, 256, 0, stream>>>(desc, nve, rnd, rnv, tb, na);
    se_attn_kernel<<<BB * 33, 256, 0, stream>>>(U, V, PK, cvec, na, sq, sk, ba,
                                                vbuf, aw, ctx);
    outgemm_kernel<<<130, 256, 0, stream>>>(ctx, WoT, bo, out);
}